// Round 4
// baseline (729.374 us; speedup 1.0000x reference)
//
#include <hip/hip_runtime.h>

typedef __bf16 bf16_t;
typedef __bf16 bf16x8 __attribute__((ext_vector_type(8)));
typedef float f32x4 __attribute__((ext_vector_type(4)));

// Problem constants: B=4, S=2048, E=1024, H=16, D=64

__device__ __forceinline__ void async_copy16(const void* g, void* l) {
  __builtin_amdgcn_global_load_lds(
      (const __attribute__((address_space(1))) void*)g,
      (__attribute__((address_space(3))) void*)l, 16, 0, 0);
}

// ---------------------------------------------------------------------------
// Fused fp32 -> bf16 convert for all 7 tensors (outputs contiguous in ws).
// Region order in ws: qb(2M quads) kb(2M) vb(2M) wkb(256K) wvb(256K) wqb(256K) wob(256K)
// ---------------------------------------------------------------------------
__global__ void cvt_all_kernel(const float* __restrict__ q, const float* __restrict__ k,
                               const float* __restrict__ v, const float* __restrict__ wk,
                               const float* __restrict__ wv, const float* __restrict__ wq,
                               const float* __restrict__ wo, uint2* __restrict__ out) {
  constexpr int QX = 2097152, QW = 262144;
  int g = blockIdx.x * 256 + threadIdx.x;
  const float* in; int off;
  if (g < QX)               { in = q;  off = 0; }
  else if (g < 2 * QX)      { in = k;  off = QX; }
  else if (g < 3 * QX)      { in = v;  off = 2 * QX; }
  else if (g < 3 * QX + QW)     { in = wk; off = 3 * QX; }
  else if (g < 3 * QX + 2 * QW) { in = wv; off = 3 * QX + QW; }
  else if (g < 3 * QX + 3 * QW) { in = wq; off = 3 * QX + 2 * QW; }
  else                          { in = wo; off = 3 * QX + 3 * QW; }
  float4 val = ((const float4*)in)[g - off];
  union { bf16_t h[4]; uint2 u; } cv;
  cv.h[0] = (bf16_t)val.x; cv.h[1] = (bf16_t)val.y;
  cv.h[2] = (bf16_t)val.z; cv.h[3] = (bf16_t)val.w;
  out[g] = cv.u;
}

// ---------------------------------------------------------------------------
// Fused Q/K/V projection GEMM. Grid (64, 24), 256 threads.
//  by>>3 == 0: Qp[B,H,S,D] = (qb @ Wq^T) * qscale
//  by>>3 == 1: Kp[B,H,S,D] =  kb @ Wk^T
//  by>>3 == 2: Vt[B,H,D,S] = (vb @ Wv^T)^T  (swapped operands)
// 128x128 tile, BK=32, 4 waves 2x2, global_load_lds width-16 staging.
// ---------------------------------------------------------------------------
__global__ __launch_bounds__(256) void qkv_kernel(
    const bf16_t* __restrict__ qb, const bf16_t* __restrict__ kb, const bf16_t* __restrict__ vb,
    const bf16_t* __restrict__ wqb, const bf16_t* __restrict__ wkb, const bf16_t* __restrict__ wvb,
    bf16_t* __restrict__ Qp, bf16_t* __restrict__ Kp, bf16_t* __restrict__ Vt, float qscale)
{
  constexpr int K = 1024;
  __shared__ __align__(16) bf16_t As[128 * 32];
  __shared__ __align__(16) bf16_t Bs[128 * 32];
  const int tid  = threadIdx.x;
  const int lane = tid & 63;
  const int wid  = tid >> 6;
  const int quad = lane >> 4;
  const int l16  = lane & 15;
  const int bx = blockIdx.x, by = blockIdx.y;
  const int sel = by >> 3, sub = by & 7;
  const bf16_t *X, *W; bf16_t* Y; float scale = 1.0f;
  int m0, n0;
  if (sel == 0)      { X = qb;  W = wqb; Y = Qp; m0 = bx * 128; n0 = sub * 128; scale = qscale; }
  else if (sel == 1) { X = kb;  W = wkb; Y = Kp; m0 = bx * 128; n0 = sub * 128; }
  else               { X = wvb; W = vb;  Y = Vt; m0 = sub * 128; n0 = bx * 128; }
  const int wm = (wid >> 1) * 64;
  const int wn = (wid & 1) * 64;

  f32x4 acc[4][4] = {};

  for (int k0 = 0; k0 < K; k0 += 32) {
#pragma unroll
    for (int p = 0; p < 2; ++p) {
      int c = tid + p * 256;
      int row = c >> 2;
      int seg = (c & 3) * 8;
      async_copy16(&X[(size_t)(m0 + row) * K + k0 + seg], (char*)As + (p * 256 + wid * 64) * 16);
      async_copy16(&W[(size_t)(n0 + row) * K + k0 + seg], (char*)Bs + (p * 256 + wid * 64) * 16);
    }
    __syncthreads();
    bf16x8 af[4], bfr[4];
#pragma unroll
    for (int i = 0; i < 4; ++i)
      af[i] = *(const bf16x8*)(&As[(wm + i * 16 + l16) * 32 + quad * 8]);
#pragma unroll
    for (int j = 0; j < 4; ++j)
      bfr[j] = *(const bf16x8*)(&Bs[(wn + j * 16 + l16) * 32 + quad * 8]);
#pragma unroll
    for (int i = 0; i < 4; ++i)
#pragma unroll
      for (int j = 0; j < 4; ++j)
        acc[i][j] = __builtin_amdgcn_mfma_f32_16x16x32_bf16(af[i], bfr[j], acc[i][j], 0, 0, 0);
    __syncthreads();
  }

#pragma unroll
  for (int i = 0; i < 4; ++i)
#pragma unroll
    for (int j = 0; j < 4; ++j)
#pragma unroll
      for (int r = 0; r < 4; ++r) {
        int row = m0 + wm + i * 16 + quad * 4 + r;
        int col = n0 + wn + j * 16 + l16;
        float val = acc[i][j][r] * scale;
        if (sel < 2) {                               // [B,H,S,D]: row=seq, col=h*64+d
          int b = row >> 11, s = row & 2047;
          int h = col >> 6,  d = col & 63;
          Y[(((size_t)(b * 16 + h) << 11) + s) * 64 + d] = (bf16_t)val;
        } else {                                     // [B,H,D,S]: row=h*64+d, col=seq
          int h = row >> 6,  d = row & 63;
          int b = col >> 11, s = col & 2047;
          Y[(((size_t)((b * 16 + h) * 64 + d)) << 11) + s] = (bf16_t)val;
        }
      }
}

// ---------------------------------------------------------------------------
// Output projection: out = Ob @ Wo^T, fp32 [M,N] row-major.
// ---------------------------------------------------------------------------
__global__ __launch_bounds__(256) void out_gemm_kernel(
    const bf16_t* __restrict__ X, const bf16_t* __restrict__ W,
    float* __restrict__ Y, int M, int N, int K)
{
  __shared__ __align__(16) bf16_t As[128 * 32];
  __shared__ __align__(16) bf16_t Bs[128 * 32];
  const int tid  = threadIdx.x;
  const int lane = tid & 63;
  const int wid  = tid >> 6;
  const int quad = lane >> 4;
  const int l16  = lane & 15;
  const int m0 = blockIdx.x * 128;
  const int n0 = blockIdx.y * 128;
  const int wm = (wid >> 1) * 64;
  const int wn = (wid & 1) * 64;

  f32x4 acc[4][4] = {};

  for (int k0 = 0; k0 < K; k0 += 32) {
#pragma unroll
    for (int p = 0; p < 2; ++p) {
      int c = tid + p * 256;
      int row = c >> 2;
      int seg = (c & 3) * 8;
      async_copy16(&X[(size_t)(m0 + row) * K + k0 + seg], (char*)As + (p * 256 + wid * 64) * 16);
      async_copy16(&W[(size_t)(n0 + row) * K + k0 + seg], (char*)Bs + (p * 256 + wid * 64) * 16);
    }
    __syncthreads();
    bf16x8 af[4], bfr[4];
#pragma unroll
    for (int i = 0; i < 4; ++i)
      af[i] = *(const bf16x8*)(&As[(wm + i * 16 + l16) * 32 + quad * 8]);
#pragma unroll
    for (int j = 0; j < 4; ++j)
      bfr[j] = *(const bf16x8*)(&Bs[(wn + j * 16 + l16) * 32 + quad * 8]);
#pragma unroll
    for (int i = 0; i < 4; ++i)
#pragma unroll
      for (int j = 0; j < 4; ++j)
        acc[i][j] = __builtin_amdgcn_mfma_f32_16x16x32_bf16(af[i], bfr[j], acc[i][j], 0, 0, 0);
    __syncthreads();
  }

#pragma unroll
  for (int i = 0; i < 4; ++i)
#pragma unroll
    for (int j = 0; j < 4; ++j)
#pragma unroll
      for (int r = 0; r < 4; ++r) {
        int row = m0 + wm + i * 16 + quad * 4 + r;
        int col = n0 + wn + j * 16 + l16;
        Y[(size_t)row * N + col] = acc[i][j][r];
      }
}

// ---------------------------------------------------------------------------
// Causal flash attention, m=0 exp2 softmax, ones-column MFMA row sums.
// 512 threads = 8 waves, each wave owns 16 q-rows (qrow = wid*16) -> the
// diagonal-tile skip is wave-uniform: jlim = wid, kklim = wid>>1.
// Qp/Kp [B,H,S,D] bf16 (Q pre-scaled by log2e/8), Vt [B,H,D,S] bf16.
// LDS 67.6 KB -> 2 blocks/CU = 16 waves/CU.
// ---------------------------------------------------------------------------
__global__ __launch_bounds__(512, 4) void attn_kernel(
    const bf16_t* __restrict__ Qp, const bf16_t* __restrict__ Kp,
    const bf16_t* __restrict__ Vt, bf16_t* __restrict__ O)
{
  constexpr int S = 2048, D = 64, E = 1024;
  constexpr int BQ = 128, BK = 128, PST = 136;
  __shared__ __align__(16) bf16_t Ks[BK * D];      // 16 KB, swizzle (c>>3)
  __shared__ __align__(16) bf16_t Vs[D * BK];      // 16 KB, swizzle (c>>4)
  __shared__ __align__(16) bf16_t Ps[BQ * PST];    // 34 KB, stride 136

  const int tid = threadIdx.x, lane = tid & 63, wid = tid >> 6;
  const int quad = lane >> 4, l16 = lane & 15;
  const int bh = blockIdx.y;
  const int b = bh >> 4, h = bh & 15;
  const int qt = gridDim.x - 1 - blockIdx.x;       // heavy causal tiles first
  const int q0 = qt * BQ;
  const size_t base  = (size_t)bh * S * D;
  const size_t baseV = (size_t)bh * D * S;
  const int qrow = wid * 16;                       // wave's 16 rows

  // Q fragments straight from global (A-layout: m=l16, k=quad*8+j)
  bf16x8 qf[2];
#pragma unroll
  for (int kk = 0; kk < 2; ++kk)
    qf[kk] = *(const bf16x8*)(&Qp[base + (size_t)(q0 + qrow + l16) * D + kk * 32 + quad * 8]);

  // stage K/V tile 0 (XOR-swizzled dest chunks); 1024 chunks over 512 threads
#pragma unroll
  for (int p = 0; p < 2; ++p) {
    int c = tid + p * 512;
    int gk = c ^ ((c >> 3) & 7);
    async_copy16(&Kp[base + (size_t)(gk >> 3) * D + (gk & 7) * 8],
                 (char*)Ks + (p * 512 + wid * 64) * 16);
    int gv = c ^ ((c >> 4) & 7);
    async_copy16(&Vt[baseV + (size_t)(gv >> 4) * S + (gv & 15) * 8],
                 (char*)Vs + (p * 512 + wid * 64) * 16);
  }
  __syncthreads();

  f32x4 o_acc[4] = {};
  f32x4 o_sum = {};
  bf16x8 ones;
#pragma unroll
  for (int e = 0; e < 8; ++e) ones[e] = (bf16_t)1.0f;

  const int nkt = qt + 1;                          // diagonal tile is last
  for (int kt = 0; kt < nkt; ++kt) {
    const bool diag = (kt == nkt - 1);
    const int jlim  = diag ? wid : 7;              // j-tiles > jlim fully masked
    const int kklim = diag ? (wid >> 1) : 3;       // PV kk-blocks with any live P
    // ---- S = Q K^T  (log2 domain) ---------------------------------------
    f32x4 sc[8] = {};
#pragma unroll
    for (int kk = 0; kk < 2; ++kk)
#pragma unroll
      for (int j = 0; j < 8; ++j)
        if (j <= jlim) {
          int L = (j * 16 + l16) * 8 + kk * 4 + quad;
          bf16x8 bk = *(const bf16x8*)(&Ks[(L ^ (l16 & 7)) * 8]);
          sc[j] = __builtin_amdgcn_mfma_f32_16x16x32_bf16(qf[kk], bk, sc[j], 0, 0, 0);
        }
    if (diag) {                                    // mask j == wid: key=qrow+l16, row=qrow+quad*4+r
#pragma unroll
      for (int r = 0; r < 4; ++r)
        if (l16 > quad * 4 + r) sc[wid][r] = -1e30f;
    }
    // ---- P = exp2(S) -> LDS ---------------------------------------------
    const int jstore = diag ? (2 * kklim + 1) : 7; // zero-fill only what PV reads
#pragma unroll
    for (int j = 0; j < 8; ++j)
      if (j <= jstore) {
        int kcol = j * 16 + l16;
#pragma unroll
        for (int r = 0; r < 4; ++r) {
          float pp = (j <= jlim) ? __builtin_amdgcn_exp2f(sc[j][r]) : 0.0f;
          Ps[(qrow + quad * 4 + r) * PST + kcol] = (bf16_t)pp;
        }
      }
    __syncthreads();                               // Ks reads done (all waves)
    // prefetch next K tile while PV computes
    if (kt + 1 < nkt) {
      const int k0n = (kt + 1) * BK;
#pragma unroll
      for (int p = 0; p < 2; ++p) {
        int c = tid + p * 512;
        int gk = c ^ ((c >> 3) & 7);
        async_copy16(&Kp[base + (size_t)(k0n + (gk >> 3)) * D + (gk & 7) * 8],
                     (char*)Ks + (p * 512 + wid * 64) * 16);
      }
    }
    // ---- O += P V ; l += P 1 --------------------------------------------
#pragma unroll
    for (int kk = 0; kk < 4; ++kk)
      if (kk <= kklim) {
        bf16x8 ap = *(const bf16x8*)(&Ps[(qrow + l16) * PST + kk * 32 + quad * 8]);
#pragma unroll
        for (int t = 0; t < 4; ++t) {
          int L = (t * 16 + l16) * 16 + kk * 4 + quad;
          bf16x8 bv = *(const bf16x8*)(&Vs[(L ^ (l16 & 7)) * 8]);
          o_acc[t] = __builtin_amdgcn_mfma_f32_16x16x32_bf16(ap, bv, o_acc[t], 0, 0, 0);
        }
        o_sum = __builtin_amdgcn_mfma_f32_16x16x32_bf16(ap, ones, o_sum, 0, 0, 0);
      }
    __syncthreads();                               // Vs reads done; drains K-async
    if (kt + 1 < nkt) {
      const int k0n = (kt + 1) * BK;
#pragma unroll
      for (int p = 0; p < 2; ++p) {
        int c = tid + p * 512;
        int gv = c ^ ((c >> 4) & 7);
        async_copy16(&Vt[baseV + (size_t)(gv >> 4) * S + k0n + (gv & 15) * 8],
                     (char*)Vs + (p * 512 + wid * 64) * 16);
      }
      __syncthreads();                             // V staged for next iter
    }
  }

  // ---- epilogue: O / rowsum ---------------------------------------------
#pragma unroll
  for (int t = 0; t < 4; ++t)
#pragma unroll
    for (int r = 0; r < 4; ++r) {
      int row = q0 + qrow + quad * 4 + r;
      int d = t * 16 + l16;
      float val = o_acc[t][r] / o_sum[r];
      O[((size_t)(b * S + row)) * E + h * D + d] = (bf16_t)val;
    }
}

// ---------------------------------------------------------------------------
extern "C" void kernel_launch(void* const* d_in, const int* in_sizes, int n_in,
                              void* d_out, int out_size, void* d_ws, size_t ws_size,
                              hipStream_t stream) {
  // setup_inputs order: k, v, q, Wk, Wv, Wq, Wo  (all fp32)
  const float* k_in = (const float*)d_in[0];
  const float* v_in = (const float*)d_in[1];
  const float* q_in = (const float*)d_in[2];
  const float* Wk_in = (const float*)d_in[3];
  const float* Wv_in = (const float*)d_in[4];
  const float* Wq_in = (const float*)d_in[5];
  const float* Wo_in = (const float*)d_in[6];
  float* out = (float*)d_out;

  constexpr int    M = 8192, N = 1024, K = 1024;
  constexpr size_t SZ_X = (size_t)M * K * 2;
  constexpr size_t SZ_W = (size_t)N * K * 2;

  char* ws = (char*)d_ws;
  bf16_t* qb  = (bf16_t*)(ws);
  bf16_t* kb  = (bf16_t*)(ws + SZ_X);
  bf16_t* vb  = (bf16_t*)(ws + 2 * SZ_X);
  bf16_t* wkb = (bf16_t*)(ws + 3 * SZ_X);
  bf16_t* wvb = (bf16_t*)(ws + 3 * SZ_X + SZ_W);
  bf16_t* wqb = (bf16_t*)(ws + 3 * SZ_X + 2 * SZ_W);
  bf16_t* wob = (bf16_t*)(ws + 3 * SZ_X + 3 * SZ_W);
  bf16_t* Qp  = (bf16_t*)(ws + 3 * SZ_X + 4 * SZ_W);
  bf16_t* Kp  = (bf16_t*)(ws + 4 * SZ_X + 4 * SZ_W);
  bf16_t* Vtg = (bf16_t*)(ws + 5 * SZ_X + 4 * SZ_W);
  bf16_t* Ob  = qb;    // qb dead after Q projection

  // 1 fused convert: 7,340,032 quads / 256 = 28672 blocks
  cvt_all_kernel<<<28672, 256, 0, stream>>>(q_in, k_in, v_in, Wk_in, Wv_in, Wq_in, Wo_in,
                                            (uint2*)ws);

  // Q scale = (1/sqrt(D)) * log2(e): scores land in log2 domain for exp2 softmax
  qkv_kernel<<<dim3(64, 24), 256, 0, stream>>>(qb, kb, vb, wqb, wkb, wvb,
                                               Qp, Kp, Vtg, 0.125f * 1.44269504f);

  attn_kernel<<<dim3(2048 / 128, 4 * 16), 512, 0, stream>>>(Qp, Kp, Vtg, Ob);

  out_gemm_kernel<<<dim3(M / 128, N / 128), 256, 0, stream>>>(Ob, wob, out, M, N, K);
}

// Round 5
// 674.474 us; speedup vs baseline: 1.0814x; 1.0814x over previous
//
#include <hip/hip_runtime.h>

typedef __bf16 bf16_t;
typedef __bf16 bf16x8 __attribute__((ext_vector_type(8)));
typedef float f32x4 __attribute__((ext_vector_type(4)));

// Problem constants: B=4, S=2048, E=1024, H=16, D=64

__device__ __forceinline__ void async_copy16(const void* g, void* l) {
  __builtin_amdgcn_global_load_lds(
      (const __attribute__((address_space(1))) void*)g,
      (__attribute__((address_space(3))) void*)l, 16, 0, 0);
}

// ---------------------------------------------------------------------------
// Fused fp32 -> bf16 convert for all 7 tensors (outputs contiguous in ws).
// ---------------------------------------------------------------------------
__global__ void cvt_all_kernel(const float* __restrict__ q, const float* __restrict__ k,
                               const float* __restrict__ v, const float* __restrict__ wk,
                               const float* __restrict__ wv, const float* __restrict__ wq,
                               const float* __restrict__ wo, uint2* __restrict__ out) {
  constexpr int QX = 2097152, QW = 262144;
  int g = blockIdx.x * 256 + threadIdx.x;
  const float* in; int off;
  if (g < QX)               { in = q;  off = 0; }
  else if (g < 2 * QX)      { in = k;  off = QX; }
  else if (g < 3 * QX)      { in = v;  off = 2 * QX; }
  else if (g < 3 * QX + QW)     { in = wk; off = 3 * QX; }
  else if (g < 3 * QX + 2 * QW) { in = wv; off = 3 * QX + QW; }
  else if (g < 3 * QX + 3 * QW) { in = wq; off = 3 * QX + 2 * QW; }
  else                          { in = wo; off = 3 * QX + 3 * QW; }
  float4 val = ((const float4*)in)[g - off];
  union { bf16_t h[4]; uint2 u; } cv;
  cv.h[0] = (bf16_t)val.x; cv.h[1] = (bf16_t)val.y;
  cv.h[2] = (bf16_t)val.z; cv.h[3] = (bf16_t)val.w;
  out[g] = cv.u;
}

// ---------------------------------------------------------------------------
// GEMM body macro pieces. 128x128 tile, BK=32, 4 waves 2x2.
// LDS chunk placement XOR-swizzled: natural chunk (row, seg) stored at
// position row*4 + (seg ^ ((row>>1)&3)). Staging inverts at the global
// source (dest stays base+lane*16). Fragment ds_read_b128 then lands in a
// distinct 4-bank group per (l16 low 3 bits) -> 2-way only (free, m136).
// ---------------------------------------------------------------------------

// ---------------------------------------------------------------------------
// Fused Q/K/V projection GEMM. Grid (64, 24), 256 threads.
//  by>>3 == 0: Qp[B,H,S,D] = (qb @ Wq^T) * qscale
//  by>>3 == 1: Kp[B,H,S,D] =  kb @ Wk^T
//  by>>3 == 2: Vt[B,H,D,S] = (vb @ Wv^T)^T  (swapped operands)
// ---------------------------------------------------------------------------
__global__ __launch_bounds__(256) void qkv_kernel(
    const bf16_t* __restrict__ qb, const bf16_t* __restrict__ kb, const bf16_t* __restrict__ vb,
    const bf16_t* __restrict__ wqb, const bf16_t* __restrict__ wkb, const bf16_t* __restrict__ wvb,
    bf16_t* __restrict__ Qp, bf16_t* __restrict__ Kp, bf16_t* __restrict__ Vt, float qscale)
{
  constexpr int K = 1024;
  __shared__ __align__(16) bf16_t As[128 * 32];
  __shared__ __align__(16) bf16_t Bs[128 * 32];
  const int tid  = threadIdx.x;
  const int lane = tid & 63;
  const int wid  = tid >> 6;
  const int quad = lane >> 4;
  const int l16  = lane & 15;
  const int bx = blockIdx.x, by = blockIdx.y;
  const int sel = by >> 3, sub = by & 7;
  const bf16_t *X, *W; bf16_t* Y; float scale = 1.0f;
  int m0, n0;
  if (sel == 0)      { X = qb;  W = wqb; Y = Qp; m0 = bx * 128; n0 = sub * 128; scale = qscale; }
  else if (sel == 1) { X = kb;  W = wkb; Y = Kp; m0 = bx * 128; n0 = sub * 128; }
  else               { X = wvb; W = vb;  Y = Vt; m0 = sub * 128; n0 = bx * 128; }
  const int wm = (wid >> 1) * 64;
  const int wn = (wid & 1) * 64;
  const int swz = quad ^ ((l16 >> 1) & 3);     // per-lane fragment swizzle

  f32x4 acc[4][4] = {};

  for (int k0 = 0; k0 < K; k0 += 32) {
#pragma unroll
    for (int p = 0; p < 2; ++p) {
      int c = tid + p * 256;                   // dest chunk (linear)
      int row = c >> 2;
      int seg = ((c & 3) ^ ((c >> 3) & 3)) * 8;  // swizzle-inverted source seg
      async_copy16(&X[(size_t)(m0 + row) * K + k0 + seg], (char*)As + (p * 256 + wid * 64) * 16);
      async_copy16(&W[(size_t)(n0 + row) * K + k0 + seg], (char*)Bs + (p * 256 + wid * 64) * 16);
    }
    __syncthreads();
    bf16x8 af[4], bfr[4];
#pragma unroll
    for (int i = 0; i < 4; ++i)
      af[i] = *(const bf16x8*)((const char*)As + ((wm + i * 16 + l16) * 4 + swz) * 16);
#pragma unroll
    for (int j = 0; j < 4; ++j)
      bfr[j] = *(const bf16x8*)((const char*)Bs + ((wn + j * 16 + l16) * 4 + swz) * 16);
#pragma unroll
    for (int i = 0; i < 4; ++i)
#pragma unroll
      for (int j = 0; j < 4; ++j)
        acc[i][j] = __builtin_amdgcn_mfma_f32_16x16x32_bf16(af[i], bfr[j], acc[i][j], 0, 0, 0);
    __syncthreads();
  }

#pragma unroll
  for (int i = 0; i < 4; ++i)
#pragma unroll
    for (int j = 0; j < 4; ++j)
#pragma unroll
      for (int r = 0; r < 4; ++r) {
        int row = m0 + wm + i * 16 + quad * 4 + r;
        int col = n0 + wn + j * 16 + l16;
        float val = acc[i][j][r] * scale;
        if (sel < 2) {                               // [B,H,S,D]
          int b = row >> 11, s = row & 2047;
          int h = col >> 6,  d = col & 63;
          Y[(((size_t)(b * 16 + h) << 11) + s) * 64 + d] = (bf16_t)val;
        } else {                                     // [B,H,D,S]
          int h = row >> 6,  d = row & 63;
          int b = col >> 11, s = col & 2047;
          Y[(((size_t)((b * 16 + h) * 64 + d)) << 11) + s] = (bf16_t)val;
        }
      }
}

// ---------------------------------------------------------------------------
// Output projection: out = Ob @ Wo^T, fp32 [M,N] row-major. Same swizzle.
// ---------------------------------------------------------------------------
__global__ __launch_bounds__(256) void out_gemm_kernel(
    const bf16_t* __restrict__ X, const bf16_t* __restrict__ W,
    float* __restrict__ Y, int M, int N, int K)
{
  __shared__ __align__(16) bf16_t As[128 * 32];
  __shared__ __align__(16) bf16_t Bs[128 * 32];
  const int tid  = threadIdx.x;
  const int lane = tid & 63;
  const int wid  = tid >> 6;
  const int quad = lane >> 4;
  const int l16  = lane & 15;
  const int m0 = blockIdx.x * 128;
  const int n0 = blockIdx.y * 128;
  const int wm = (wid >> 1) * 64;
  const int wn = (wid & 1) * 64;
  const int swz = quad ^ ((l16 >> 1) & 3);

  f32x4 acc[4][4] = {};

  for (int k0 = 0; k0 < K; k0 += 32) {
#pragma unroll
    for (int p = 0; p < 2; ++p) {
      int c = tid + p * 256;
      int row = c >> 2;
      int seg = ((c & 3) ^ ((c >> 3) & 3)) * 8;
      async_copy16(&X[(size_t)(m0 + row) * K + k0 + seg], (char*)As + (p * 256 + wid * 64) * 16);
      async_copy16(&W[(size_t)(n0 + row) * K + k0 + seg], (char*)Bs + (p * 256 + wid * 64) * 16);
    }
    __syncthreads();
    bf16x8 af[4], bfr[4];
#pragma unroll
    for (int i = 0; i < 4; ++i)
      af[i] = *(const bf16x8*)((const char*)As + ((wm + i * 16 + l16) * 4 + swz) * 16);
#pragma unroll
    for (int j = 0; j < 4; ++j)
      bfr[j] = *(const bf16x8*)((const char*)Bs + ((wn + j * 16 + l16) * 4 + swz) * 16);
#pragma unroll
    for (int i = 0; i < 4; ++i)
#pragma unroll
      for (int j = 0; j < 4; ++j)
        acc[i][j] = __builtin_amdgcn_mfma_f32_16x16x32_bf16(af[i], bfr[j], acc[i][j], 0, 0, 0);
    __syncthreads();
  }

#pragma unroll
  for (int i = 0; i < 4; ++i)
#pragma unroll
    for (int j = 0; j < 4; ++j)
#pragma unroll
      for (int r = 0; r < 4; ++r) {
        int row = m0 + wm + i * 16 + quad * 4 + r;
        int col = n0 + wn + j * 16 + l16;
        Y[(size_t)row * N + col] = acc[i][j][r];
      }
}

// ---------------------------------------------------------------------------
// Causal flash attention, m=0 exp2 softmax, ones-column MFMA row sums.
// Round-3 proven shape: 256 threads / 4 waves, wave owns 32 rows (2 row-tiles),
// __launch_bounds__(256,2) -> VGPR ~104, no spills. NEW: wave-uniform
// diagonal-tile skip per row-tile: jlim(rt)=2*wid+rt, kklim=wid.
// ---------------------------------------------------------------------------
__global__ __launch_bounds__(256, 2) void attn_kernel(
    const bf16_t* __restrict__ Qp, const bf16_t* __restrict__ Kp,
    const bf16_t* __restrict__ Vt, bf16_t* __restrict__ O)
{
  constexpr int S = 2048, D = 64, E = 1024;
  constexpr int BQ = 128, BK = 128, PST = 136;
  __shared__ __align__(16) bf16_t Ks[BK * D];      // 16 KB, swizzle (c>>3)
  __shared__ __align__(16) bf16_t Vs[D * BK];      // 16 KB, swizzle (c>>4)
  __shared__ __align__(16) bf16_t Ps[BQ * PST];    // 34 KB, stride 136

  const int tid = threadIdx.x, lane = tid & 63, wid = tid >> 6;
  const int quad = lane >> 4, l16 = lane & 15;
  const int bh = blockIdx.y;
  const int b = bh >> 4, h = bh & 15;
  const int qt = gridDim.x - 1 - blockIdx.x;       // heavy causal tiles first
  const int q0 = qt * BQ;
  const size_t base  = (size_t)bh * S * D;
  const size_t baseV = (size_t)bh * D * S;
  const int qrow = wid * 32;

  // Q fragments straight from global (A-layout: m=l16, k=quad*8+j)
  bf16x8 qf[2][2];
#pragma unroll
  for (int rt = 0; rt < 2; ++rt)
#pragma unroll
    for (int kk = 0; kk < 2; ++kk)
      qf[rt][kk] = *(const bf16x8*)(&Qp[base + (size_t)(q0 + qrow + rt * 16 + l16) * D + kk * 32 + quad * 8]);

  // stage K/V tile 0 (XOR-swizzled dest chunks)
#pragma unroll
  for (int p = 0; p < 4; ++p) {
    int c = tid + p * 256;
    int gk = c ^ ((c >> 3) & 7);
    async_copy16(&Kp[base + (size_t)(gk >> 3) * D + (gk & 7) * 8],
                 (char*)Ks + (p * 256 + wid * 64) * 16);
    int gv = c ^ ((c >> 4) & 7);
    async_copy16(&Vt[baseV + (size_t)(gv >> 4) * S + (gv & 15) * 8],
                 (char*)Vs + (p * 256 + wid * 64) * 16);
  }
  __syncthreads();

  f32x4 o_acc[2][4] = {};
  f32x4 o_sum[2] = {};
  bf16x8 ones;
#pragma unroll
  for (int e = 0; e < 8; ++e) ones[e] = (bf16_t)1.0f;

  const int nkt = qt + 1;                          // diagonal tile is last
  for (int kt = 0; kt < nkt; ++kt) {
    const bool diag = (kt == nkt - 1);
    const int jlim0 = diag ? 2 * wid     : 7;      // live j-tiles, row-tile 0
    const int jlim1 = diag ? 2 * wid + 1 : 7;      // live j-tiles, row-tile 1
    const int kklim = diag ? wid : 3;              // live PV kk-blocks
    // ---- S = Q K^T  (log2 domain) ---------------------------------------
    f32x4 sc[2][8] = {};
#pragma unroll
    for (int kk = 0; kk < 2; ++kk)
#pragma unroll
      for (int j = 0; j < 8; ++j)
        if (j <= jlim1) {
          int L = (j * 16 + l16) * 8 + kk * 4 + quad;
          bf16x8 bk = *(const bf16x8*)(&Ks[(L ^ (l16 & 7)) * 8]);
          if (j <= jlim0)
            sc[0][j] = __builtin_amdgcn_mfma_f32_16x16x32_bf16(qf[0][kk], bk, sc[0][j], 0, 0, 0);
          sc[1][j] = __builtin_amdgcn_mfma_f32_16x16x32_bf16(qf[1][kk], bk, sc[1][j], 0, 0, 0);
        }
    if (diag) {                                    // mask the diagonal j-tile of each row-tile
#pragma unroll
      for (int r = 0; r < 4; ++r) {
        if (l16 > quad * 4 + r) sc[0][2 * wid][r]     = -1e30f;
        if (l16 > quad * 4 + r) sc[1][2 * wid + 1][r] = -1e30f;
      }
    }
    // ---- P = exp2(S) -> LDS (zero-fill only what PV reads) --------------
#pragma unroll
    for (int rt = 0; rt < 2; ++rt) {
      const int jlive = rt ? jlim1 : jlim0;
#pragma unroll
      for (int j = 0; j < 8; ++j)
        if (j <= jlim1) {
          int kcol = j * 16 + l16;
#pragma unroll
          for (int r = 0; r < 4; ++r) {
            float pp = (j <= jlive) ? __builtin_amdgcn_exp2f(sc[rt][j][r]) : 0.0f;
            Ps[(qrow + rt * 16 + quad * 4 + r) * PST + kcol] = (bf16_t)pp;
          }
        }
    }
    __syncthreads();                               // Ks reads done (all waves)
    // prefetch next K tile while PV computes
    if (kt + 1 < nkt) {
      const int k0n = (kt + 1) * BK;
#pragma unroll
      for (int p = 0; p < 4; ++p) {
        int c = tid + p * 256;
        int gk = c ^ ((c >> 3) & 7);
        async_copy16(&Kp[base + (size_t)(k0n + (gk >> 3)) * D + (gk & 7) * 8],
                     (char*)Ks + (p * 256 + wid * 64) * 16);
      }
    }
    // ---- O += P V ; l += P 1 --------------------------------------------
#pragma unroll
    for (int kk = 0; kk < 4; ++kk)
      if (kk <= kklim) {
        bf16x8 ap0 = *(const bf16x8*)(&Ps[(qrow + l16) * PST + kk * 32 + quad * 8]);
        bf16x8 ap1 = *(const bf16x8*)(&Ps[(qrow + 16 + l16) * PST + kk * 32 + quad * 8]);
#pragma unroll
        for (int t = 0; t < 4; ++t) {
          int L = (t * 16 + l16) * 16 + kk * 4 + quad;
          bf16x8 bv = *(const bf16x8*)(&Vs[(L ^ (l16 & 7)) * 8]);
          o_acc[0][t] = __builtin_amdgcn_mfma_f32_16x16x32_bf16(ap0, bv, o_acc[0][t], 0, 0, 0);
          o_acc[1][t] = __builtin_amdgcn_mfma_f32_16x16x32_bf16(ap1, bv, o_acc[1][t], 0, 0, 0);
        }
        o_sum[0] = __builtin_amdgcn_mfma_f32_16x16x32_bf16(ap0, ones, o_sum[0], 0, 0, 0);
        o_sum[1] = __builtin_amdgcn_mfma_f32_16x16x32_bf16(ap1, ones, o_sum[1], 0, 0, 0);
      }
    __syncthreads();                               // Vs reads done; drains K-async
    if (kt + 1 < nkt) {
      const int k0n = (kt + 1) * BK;
#pragma unroll
      for (int p = 0; p < 4; ++p) {
        int c = tid + p * 256;
        int gv = c ^ ((c >> 4) & 7);
        async_copy16(&Vt[baseV + (size_t)(gv >> 4) * S + k0n + (gv & 15) * 8],
                     (char*)Vs + (p * 256 + wid * 64) * 16);
      }
      __syncthreads();                             // V staged for next iter
    }
  }

  // ---- epilogue: O / rowsum ---------------------------------------------
#pragma unroll
  for (int rt = 0; rt < 2; ++rt)
#pragma unroll
    for (int t = 0; t < 4; ++t)
#pragma unroll
      for (int r = 0; r < 4; ++r) {
        int row = q0 + qrow + rt * 16 + quad * 4 + r;
        int d = t * 16 + l16;
        float val = o_acc[rt][t][r] / o_sum[rt][r];
        O[((size_t)(b * S + row)) * E + h * D + d] = (bf16_t)val;
      }
}

// ---------------------------------------------------------------------------
extern "C" void kernel_launch(void* const* d_in, const int* in_sizes, int n_in,
                              void* d_out, int out_size, void* d_ws, size_t ws_size,
                              hipStream_t stream) {
  // setup_inputs order: k, v, q, Wk, Wv, Wq, Wo  (all fp32)
  const float* k_in = (const float*)d_in[0];
  const float* v_in = (const float*)d_in[1];
  const float* q_in = (const float*)d_in[2];
  const float* Wk_in = (const float*)d_in[3];
  const float* Wv_in = (const float*)d_in[4];
  const float* Wq_in = (const float*)d_in[5];
  const float* Wo_in = (const float*)d_in[6];
  float* out = (float*)d_out;

  constexpr int    M = 8192, N = 1024, K = 1024;
  constexpr size_t SZ_X = (size_t)M * K * 2;
  constexpr size_t SZ_W = (size_t)N * K * 2;

  char* ws = (char*)d_ws;
  bf16_t* qb  = (bf16_t*)(ws);
  bf16_t* kb  = (bf16_t*)(ws + SZ_X);
  bf16_t* vb  = (bf16_t*)(ws + 2 * SZ_X);
  bf16_t* wkb = (bf16_t*)(ws + 3 * SZ_X);
  bf16_t* wvb = (bf16_t*)(ws + 3 * SZ_X + SZ_W);
  bf16_t* wqb = (bf16_t*)(ws + 3 * SZ_X + 2 * SZ_W);
  bf16_t* wob = (bf16_t*)(ws + 3 * SZ_X + 3 * SZ_W);
  bf16_t* Qp  = (bf16_t*)(ws + 3 * SZ_X + 4 * SZ_W);
  bf16_t* Kp  = (bf16_t*)(ws + 4 * SZ_X + 4 * SZ_W);
  bf16_t* Vtg = (bf16_t*)(ws + 5 * SZ_X + 4 * SZ_W);
  bf16_t* Ob  = qb;    // qb dead after Q projection

  cvt_all_kernel<<<28672, 256, 0, stream>>>(q_in, k_in, v_in, Wk_in, Wv_in, Wq_in, Wo_in,
                                            (uint2*)ws);

  // Q scale = (1/sqrt(D)) * log2(e): scores in log2 domain for exp2 softmax
  qkv_kernel<<<dim3(64, 24), 256, 0, stream>>>(qb, kb, vb, wqb, wkb, wvb,
                                               Qp, Kp, Vtg, 0.125f * 1.44269504f);

  attn_kernel<<<dim3(2048 / 128, 4 * 16), 256, 0, stream>>>(Qp, Kp, Vtg, Ob);

  out_gemm_kernel<<<dim3(M / 128, N / 128), 256, 0, stream>>>(Ob, wob, out, M, N, K);
}

// Round 6
// 339.207 us; speedup vs baseline: 2.1502x; 1.9884x over previous
//
#include <hip/hip_runtime.h>

typedef __bf16 bf16_t;
typedef __bf16 bf16x8 __attribute__((ext_vector_type(8)));
typedef float f32x4 __attribute__((ext_vector_type(4)));

// Problem constants: B=4, S=2048, E=1024, H=16, D=64

__device__ __forceinline__ void async_copy16(const void* g, void* l) {
  __builtin_amdgcn_global_load_lds(
      (const __attribute__((address_space(1))) void*)g,
      (__attribute__((address_space(3))) void*)l, 16, 0, 0);
}

// ---------------------------------------------------------------------------
// Fused fp32 -> bf16 convert for all 7 tensors (outputs contiguous in ws).
// ---------------------------------------------------------------------------
__global__ void cvt_all_kernel(const float* __restrict__ q, const float* __restrict__ k,
                               const float* __restrict__ v, const float* __restrict__ wk,
                               const float* __restrict__ wv, const float* __restrict__ wq,
                               const float* __restrict__ wo, uint2* __restrict__ out) {
  constexpr int QX = 2097152, QW = 262144;
  int g = blockIdx.x * 256 + threadIdx.x;
  const float* in; int off;
  if (g < QX)               { in = q;  off = 0; }
  else if (g < 2 * QX)      { in = k;  off = QX; }
  else if (g < 3 * QX)      { in = v;  off = 2 * QX; }
  else if (g < 3 * QX + QW)     { in = wk; off = 3 * QX; }
  else if (g < 3 * QX + 2 * QW) { in = wv; off = 3 * QX + QW; }
  else if (g < 3 * QX + 3 * QW) { in = wq; off = 3 * QX + 2 * QW; }
  else                          { in = wo; off = 3 * QX + 3 * QW; }
  float4 val = ((const float4*)in)[g - off];
  union { bf16_t h[4]; uint2 u; } cv;
  cv.h[0] = (bf16_t)val.x; cv.h[1] = (bf16_t)val.y;
  cv.h[2] = (bf16_t)val.z; cv.h[3] = (bf16_t)val.w;
  out[g] = cv.u;
}

// ---------------------------------------------------------------------------
// Fused Q/K/V projection GEMM. Grid (64, 24), 256 threads.
//  by>>3 == 0: Qp[B,H,S,D] = (qb @ Wq^T) * qscale
//  by>>3 == 1: Kp[B,H,S,D] =  kb @ Wk^T
//  by>>3 == 2: Vt[B,H,D,S] = (vb @ Wv^T)^T  (swapped operands)
// 128x128 tile, BK=32. LDS chunk placement XOR-swizzled (inverted at the
// global source; dest stays base+lane*16): fragment ds_read_b128 -> 2-way.
// ---------------------------------------------------------------------------
__global__ __launch_bounds__(256) void qkv_kernel(
    const bf16_t* __restrict__ qb, const bf16_t* __restrict__ kb, const bf16_t* __restrict__ vb,
    const bf16_t* __restrict__ wqb, const bf16_t* __restrict__ wkb, const bf16_t* __restrict__ wvb,
    bf16_t* __restrict__ Qp, bf16_t* __restrict__ Kp, bf16_t* __restrict__ Vt, float qscale)
{
  constexpr int K = 1024;
  __shared__ __align__(16) bf16_t As[128 * 32];
  __shared__ __align__(16) bf16_t Bs[128 * 32];
  const int tid  = threadIdx.x;
  const int lane = tid & 63;
  const int wid  = tid >> 6;
  const int quad = lane >> 4;
  const int l16  = lane & 15;
  const int bx = blockIdx.x, by = blockIdx.y;
  const int sel = by >> 3, sub = by & 7;
  const bf16_t *X, *W; bf16_t* Y; float scale = 1.0f;
  int m0, n0;
  if (sel == 0)      { X = qb;  W = wqb; Y = Qp; m0 = bx * 128; n0 = sub * 128; scale = qscale; }
  else if (sel == 1) { X = kb;  W = wkb; Y = Kp; m0 = bx * 128; n0 = sub * 128; }
  else               { X = wvb; W = vb;  Y = Vt; m0 = sub * 128; n0 = bx * 128; }
  const int wm = (wid >> 1) * 64;
  const int wn = (wid & 1) * 64;
  const int swz = quad ^ ((l16 >> 1) & 3);     // per-lane fragment swizzle

  f32x4 acc[4][4] = {};

  for (int k0 = 0; k0 < K; k0 += 32) {
#pragma unroll
    for (int p = 0; p < 2; ++p) {
      int c = tid + p * 256;                   // dest chunk (linear)
      int row = c >> 2;
      int seg = ((c & 3) ^ ((c >> 3) & 3)) * 8;  // swizzle-inverted source seg
      async_copy16(&X[(size_t)(m0 + row) * K + k0 + seg], (char*)As + (p * 256 + wid * 64) * 16);
      async_copy16(&W[(size_t)(n0 + row) * K + k0 + seg], (char*)Bs + (p * 256 + wid * 64) * 16);
    }
    __syncthreads();
    bf16x8 af[4], bfr[4];
#pragma unroll
    for (int i = 0; i < 4; ++i)
      af[i] = *(const bf16x8*)((const char*)As + ((wm + i * 16 + l16) * 4 + swz) * 16);
#pragma unroll
    for (int j = 0; j < 4; ++j)
      bfr[j] = *(const bf16x8*)((const char*)Bs + ((wn + j * 16 + l16) * 4 + swz) * 16);
#pragma unroll
    for (int i = 0; i < 4; ++i)
#pragma unroll
      for (int j = 0; j < 4; ++j)
        acc[i][j] = __builtin_amdgcn_mfma_f32_16x16x32_bf16(af[i], bfr[j], acc[i][j], 0, 0, 0);
    __syncthreads();
  }

#pragma unroll
  for (int i = 0; i < 4; ++i)
#pragma unroll
    for (int j = 0; j < 4; ++j)
#pragma unroll
      for (int r = 0; r < 4; ++r) {
        int row = m0 + wm + i * 16 + quad * 4 + r;
        int col = n0 + wn + j * 16 + l16;
        float val = acc[i][j][r] * scale;
        if (sel < 2) {                               // [B,H,S,D]
          int b = row >> 11, s = row & 2047;
          int h = col >> 6,  d = col & 63;
          Y[(((size_t)(b * 16 + h) << 11) + s) * 64 + d] = (bf16_t)val;
        } else {                                     // [B,H,D,S]
          int h = row >> 6,  d = row & 63;
          int b = col >> 11, s = col & 2047;
          Y[(((size_t)((b * 16 + h) * 64 + d)) << 11) + s] = (bf16_t)val;
        }
      }
}

// ---------------------------------------------------------------------------
// Output projection: out = Ob @ Wo^T, fp32 [M,N] row-major. Same swizzle.
// ---------------------------------------------------------------------------
__global__ __launch_bounds__(256) void out_gemm_kernel(
    const bf16_t* __restrict__ X, const bf16_t* __restrict__ W,
    float* __restrict__ Y, int M, int N, int K)
{
  __shared__ __align__(16) bf16_t As[128 * 32];
  __shared__ __align__(16) bf16_t Bs[128 * 32];
  const int tid  = threadIdx.x;
  const int lane = tid & 63;
  const int wid  = tid >> 6;
  const int quad = lane >> 4;
  const int l16  = lane & 15;
  const int m0 = blockIdx.x * 128;
  const int n0 = blockIdx.y * 128;
  const int wm = (wid >> 1) * 64;
  const int wn = (wid & 1) * 64;
  const int swz = quad ^ ((l16 >> 1) & 3);

  f32x4 acc[4][4] = {};

  for (int k0 = 0; k0 < K; k0 += 32) {
#pragma unroll
    for (int p = 0; p < 2; ++p) {
      int c = tid + p * 256;
      int row = c >> 2;
      int seg = ((c & 3) ^ ((c >> 3) & 3)) * 8;
      async_copy16(&X[(size_t)(m0 + row) * K + k0 + seg], (char*)As + (p * 256 + wid * 64) * 16);
      async_copy16(&W[(size_t)(n0 + row) * K + k0 + seg], (char*)Bs + (p * 256 + wid * 64) * 16);
    }
    __syncthreads();
    bf16x8 af[4], bfr[4];
#pragma unroll
    for (int i = 0; i < 4; ++i)
      af[i] = *(const bf16x8*)((const char*)As + ((wm + i * 16 + l16) * 4 + swz) * 16);
#pragma unroll
    for (int j = 0; j < 4; ++j)
      bfr[j] = *(const bf16x8*)((const char*)Bs + ((wn + j * 16 + l16) * 4 + swz) * 16);
#pragma unroll
    for (int i = 0; i < 4; ++i)
#pragma unroll
      for (int j = 0; j < 4; ++j)
        acc[i][j] = __builtin_amdgcn_mfma_f32_16x16x32_bf16(af[i], bfr[j], acc[i][j], 0, 0, 0);
    __syncthreads();
  }

#pragma unroll
  for (int i = 0; i < 4; ++i)
#pragma unroll
    for (int j = 0; j < 4; ++j)
#pragma unroll
      for (int r = 0; r < 4; ++r) {
        int row = m0 + wm + i * 16 + quad * 4 + r;
        int col = n0 + wn + j * 16 + l16;
        Y[(size_t)row * N + col] = acc[i][j][r];
      }
}

// ---------------------------------------------------------------------------
// Causal flash attention, m=0 exp2 softmax, ones-column MFMA row sums.
// 256 threads / 4 waves, wave owns 32 rows (2 row-tiles). Diagonal-tile
// skip via wave-uniform loop bounds (jlim/kklim). Causal masking uses ONLY
// compile-time register indices (runtime-indexed sc[] demotes the score
// array to scratch: 612 MB WRITE_SIZE, 4x slowdown — rounds 4/5 post-mortem).
// ---------------------------------------------------------------------------
__global__ __launch_bounds__(256, 2) void attn_kernel(
    const bf16_t* __restrict__ Qp, const bf16_t* __restrict__ Kp,
    const bf16_t* __restrict__ Vt, bf16_t* __restrict__ O)
{
  constexpr int S = 2048, D = 64, E = 1024;
  constexpr int BQ = 128, BK = 128, PST = 136;
  __shared__ __align__(16) bf16_t Ks[BK * D];      // 16 KB, swizzle (c>>3)
  __shared__ __align__(16) bf16_t Vs[D * BK];      // 16 KB, swizzle (c>>4)
  __shared__ __align__(16) bf16_t Ps[BQ * PST];    // 34 KB, stride 136

  const int tid = threadIdx.x, lane = tid & 63, wid = tid >> 6;
  const int quad = lane >> 4, l16 = lane & 15;
  const int bh = blockIdx.y;
  const int b = bh >> 4, h = bh & 15;
  const int qt = gridDim.x - 1 - blockIdx.x;       // heavy causal tiles first
  const int q0 = qt * BQ;
  const size_t base  = (size_t)bh * S * D;
  const size_t baseV = (size_t)bh * D * S;
  const int qrow = wid * 32;

  // Q fragments straight from global (A-layout: m=l16, k=quad*8+j)
  bf16x8 qf[2][2];
#pragma unroll
  for (int rt = 0; rt < 2; ++rt)
#pragma unroll
    for (int kk = 0; kk < 2; ++kk)
      qf[rt][kk] = *(const bf16x8*)(&Qp[base + (size_t)(q0 + qrow + rt * 16 + l16) * D + kk * 32 + quad * 8]);

  // stage K/V tile 0 (XOR-swizzled dest chunks)
#pragma unroll
  for (int p = 0; p < 4; ++p) {
    int c = tid + p * 256;
    int gk = c ^ ((c >> 3) & 7);
    async_copy16(&Kp[base + (size_t)(gk >> 3) * D + (gk & 7) * 8],
                 (char*)Ks + (p * 256 + wid * 64) * 16);
    int gv = c ^ ((c >> 4) & 7);
    async_copy16(&Vt[baseV + (size_t)(gv >> 4) * S + (gv & 15) * 8],
                 (char*)Vs + (p * 256 + wid * 64) * 16);
  }
  __syncthreads();

  f32x4 o_acc[2][4] = {};
  f32x4 o_sum[2] = {};
  bf16x8 ones;
#pragma unroll
  for (int e = 0; e < 8; ++e) ones[e] = (bf16_t)1.0f;

  const int nkt = qt + 1;                          // diagonal tile is last
  for (int kt = 0; kt < nkt; ++kt) {
    const bool diag = (kt == nkt - 1);
    const int jlim0 = diag ? 2 * wid     : 7;      // live j-tiles, row-tile 0
    const int jlim1 = diag ? 2 * wid + 1 : 7;      // live j-tiles, row-tile 1
    const int kklim = diag ? wid : 3;              // live PV kk-blocks
    // ---- S = Q K^T  (log2 domain) ---------------------------------------
    f32x4 sc[2][8] = {};
#pragma unroll
    for (int kk = 0; kk < 2; ++kk)
#pragma unroll
      for (int j = 0; j < 8; ++j)
        if (j <= jlim1) {
          int L = (j * 16 + l16) * 8 + kk * 4 + quad;
          bf16x8 bk = *(const bf16x8*)(&Ks[(L ^ (l16 & 7)) * 8]);
          if (j <= jlim0)
            sc[0][j] = __builtin_amdgcn_mfma_f32_16x16x32_bf16(qf[0][kk], bk, sc[0][j], 0, 0, 0);
          sc[1][j] = __builtin_amdgcn_mfma_f32_16x16x32_bf16(qf[1][kk], bk, sc[1][j], 0, 0, 0);
        }
    if (diag) {
      // Compile-time indices only; value compare does the masking.
      // Keys j*16+l16 vs row qrow+rt*16+quad*4+r (k0 == q0 on diagonal).
#pragma unroll
      for (int rt = 0; rt < 2; ++rt)
#pragma unroll
        for (int j = 0; j < 8; ++j)
#pragma unroll
          for (int r = 0; r < 4; ++r)
            if (j * 16 + l16 > qrow + rt * 16 + quad * 4 + r) sc[rt][j][r] = -1e30f;
    }
    // ---- P = exp2(S) -> LDS (zero-fill only what PV reads) --------------
#pragma unroll
    for (int rt = 0; rt < 2; ++rt) {
      const int jlive = rt ? jlim1 : jlim0;
#pragma unroll
      for (int j = 0; j < 8; ++j)
        if (j <= jlim1) {
          int kcol = j * 16 + l16;
#pragma unroll
          for (int r = 0; r < 4; ++r) {
            float pp = (j <= jlive) ? __builtin_amdgcn_exp2f(sc[rt][j][r]) : 0.0f;
            Ps[(qrow + rt * 16 + quad * 4 + r) * PST + kcol] = (bf16_t)pp;
          }
        }
    }
    __syncthreads();                               // Ks reads done (all waves)
    // prefetch next K tile while PV computes
    if (kt + 1 < nkt) {
      const int k0n = (kt + 1) * BK;
#pragma unroll
      for (int p = 0; p < 4; ++p) {
        int c = tid + p * 256;
        int gk = c ^ ((c >> 3) & 7);
        async_copy16(&Kp[base + (size_t)(k0n + (gk >> 3)) * D + (gk & 7) * 8],
                     (char*)Ks + (p * 256 + wid * 64) * 16);
      }
    }
    // ---- O += P V ; l += P 1 --------------------------------------------
#pragma unroll
    for (int kk = 0; kk < 4; ++kk)
      if (kk <= kklim) {
        bf16x8 ap0 = *(const bf16x8*)(&Ps[(qrow + l16) * PST + kk * 32 + quad * 8]);
        bf16x8 ap1 = *(const bf16x8*)(&Ps[(qrow + 16 + l16) * PST + kk * 32 + quad * 8]);
#pragma unroll
        for (int t = 0; t < 4; ++t) {
          int L = (t * 16 + l16) * 16 + kk * 4 + quad;
          bf16x8 bv = *(const bf16x8*)(&Vs[(L ^ (l16 & 7)) * 8]);
          o_acc[0][t] = __builtin_amdgcn_mfma_f32_16x16x32_bf16(ap0, bv, o_acc[0][t], 0, 0, 0);
          o_acc[1][t] = __builtin_amdgcn_mfma_f32_16x16x32_bf16(ap1, bv, o_acc[1][t], 0, 0, 0);
        }
        o_sum[0] = __builtin_amdgcn_mfma_f32_16x16x32_bf16(ap0, ones, o_sum[0], 0, 0, 0);
        o_sum[1] = __builtin_amdgcn_mfma_f32_16x16x32_bf16(ap1, ones, o_sum[1], 0, 0, 0);
      }
    __syncthreads();                               // Vs reads done; drains K-async
    if (kt + 1 < nkt) {
      const int k0n = (kt + 1) * BK;
#pragma unroll
      for (int p = 0; p < 4; ++p) {
        int c = tid + p * 256;
        int gv = c ^ ((c >> 4) & 7);
        async_copy16(&Vt[baseV + (size_t)(gv >> 4) * S + k0n + (gv & 15) * 8],
                     (char*)Vs + (p * 256 + wid * 64) * 16);
      }
      __syncthreads();                             // V staged for next iter
    }
  }

  // ---- epilogue: O / rowsum ---------------------------------------------
#pragma unroll
  for (int rt = 0; rt < 2; ++rt)
#pragma unroll
    for (int t = 0; t < 4; ++t)
#pragma unroll
      for (int r = 0; r < 4; ++r) {
        int row = q0 + qrow + rt * 16 + quad * 4 + r;
        int d = t * 16 + l16;
        float val = o_acc[rt][t][r] / o_sum[rt][r];
        O[((size_t)(b * S + row)) * E + h * D + d] = (bf16_t)val;
      }
}

// ---------------------------------------------------------------------------
extern "C" void kernel_launch(void* const* d_in, const int* in_sizes, int n_in,
                              void* d_out, int out_size, void* d_ws, size_t ws_size,
                              hipStream_t stream) {
  // setup_inputs order: k, v, q, Wk, Wv, Wq, Wo  (all fp32)
  const float* k_in = (const float*)d_in[0];
  const float* v_in = (const float*)d_in[1];
  const float* q_in = (const float*)d_in[2];
  const float* Wk_in = (const float*)d_in[3];
  const float* Wv_in = (const float*)d_in[4];
  const float* Wq_in = (const float*)d_in[5];
  const float* Wo_in = (const float*)d_in[6];
  float* out = (float*)d_out;

  constexpr int    M = 8192, N = 1024, K = 1024;
  constexpr size_t SZ_X = (size_t)M * K * 2;
  constexpr size_t SZ_W = (size_t)N * K * 2;

  char* ws = (char*)d_ws;
  bf16_t* qb  = (bf16_t*)(ws);
  bf16_t* kb  = (bf16_t*)(ws + SZ_X);
  bf16_t* vb  = (bf16_t*)(ws + 2 * SZ_X);
  bf16_t* wkb = (bf16_t*)(ws + 3 * SZ_X);
  bf16_t* wvb = (bf16_t*)(ws + 3 * SZ_X + SZ_W);
  bf16_t* wqb = (bf16_t*)(ws + 3 * SZ_X + 2 * SZ_W);
  bf16_t* wob = (bf16_t*)(ws + 3 * SZ_X + 3 * SZ_W);
  bf16_t* Qp  = (bf16_t*)(ws + 3 * SZ_X + 4 * SZ_W);
  bf16_t* Kp  = (bf16_t*)(ws + 4 * SZ_X + 4 * SZ_W);
  bf16_t* Vtg = (bf16_t*)(ws + 5 * SZ_X + 4 * SZ_W);
  bf16_t* Ob  = qb;    // qb dead after Q projection

  cvt_all_kernel<<<28672, 256, 0, stream>>>(q_in, k_in, v_in, Wk_in, Wv_in, Wq_in, Wo_in,
                                            (uint2*)ws);

  // Q scale = (1/sqrt(D)) * log2(e): scores in log2 domain for exp2 softmax
  qkv_kernel<<<dim3(64, 24), 256, 0, stream>>>(qb, kb, vb, wqb, wkb, wvb,
                                               Qp, Kp, Vtg, 0.125f * 1.44269504f);

  attn_kernel<<<dim3(2048 / 128, 4 * 16), 256, 0, stream>>>(Qp, Kp, Vtg, Ob);

  out_gemm_kernel<<<dim3(M / 128, N / 128), 256, 0, stream>>>(Ob, wob, out, M, N, K);
}